// Round 1
// baseline (119.879 us; speedup 1.0000x reference)
//
#include <hip/hip_runtime.h>
#include <math.h>

#define NCLS 80
#define BB   32
#define NBOX 50
#define CC   85   // 5 + NUM_CLASSES

#define GRID1 2048
#define BLK1  256

__device__ __forceinline__ float clip10(float x) {
    return fminf(fmaxf(x, -10.f), 10.f);
}

// BCE with target 0: max(x,0) + log1p(exp(-|x|))
__device__ __forceinline__ float bce0(float x) {
    return fmaxf(x, 0.f) + __logf(1.f + __expf(-fabsf(x)));
}

// ---------------------------------------------------------------------------
// K1: dense base sums. For each scale s accumulate:
//   part[3s+0] = sum over ch 0..3   of clip(x)^2
//   part[3s+1] = sum over ch 4      of BCE(clip(x), 0)
//   part[3s+2] = sum over ch 5..84  of BCE(clip(x), 0)
// Per-block partials written (fp64) to ws; no atomics.
// ---------------------------------------------------------------------------
__global__ __launch_bounds__(BLK1) void base_kernel(
    const float* __restrict__ p0, const float* __restrict__ p1,
    const float* __restrict__ p2, double* __restrict__ partial)
{
    const int tid = blockIdx.x * BLK1 + threadIdx.x;
    const int nth = GRID1 * BLK1;
    const float* ps[3] = {p0, p1, p2};
    const int hw4s[3]  = {64*64/4, 32*32/4, 16*16/4};

    float part[9];
    #pragma unroll
    for (int s = 0; s < 3; ++s) {
        const float4* p = (const float4*)ps[s];
        const int hw4 = hw4s[s];
        const int n4  = BB * CC * hw4;
        float bx = 0.f, ob = 0.f, cl = 0.f;
        for (int i = tid; i < n4; i += nth) {
            float4 v = p[i];
            int c = (i / hw4) % CC;          // channel (uniform within float4)
            float a0 = clip10(v.x), a1 = clip10(v.y);
            float a2 = clip10(v.z), a3 = clip10(v.w);
            if (c < 4) {
                bx += a0*a0 + a1*a1 + a2*a2 + a3*a3;
            } else if (c == 4) {
                ob += bce0(a0) + bce0(a1) + bce0(a2) + bce0(a3);
            } else {
                cl += bce0(a0) + bce0(a1) + bce0(a2) + bce0(a3);
            }
        }
        part[3*s+0] = bx; part[3*s+1] = ob; part[3*s+2] = cl;
    }

    // wave64 shuffle reduce each of the 9 sums
    #pragma unroll
    for (int k = 0; k < 9; ++k) {
        float v = part[k];
        #pragma unroll
        for (int off = 32; off > 0; off >>= 1) v += __shfl_down(v, off);
        part[k] = v;
    }
    __shared__ float sred[BLK1/64][9];
    const int wave = threadIdx.x >> 6;
    const int lane = threadIdx.x & 63;
    if (lane == 0) {
        #pragma unroll
        for (int k = 0; k < 9; ++k) sred[wave][k] = part[k];
    }
    __syncthreads();
    if (threadIdx.x == 0) {
        double* o = partial + (size_t)blockIdx.x * 9;
        #pragma unroll
        for (int k = 0; k < 9; ++k)
            o[k] = (double)(sred[0][k] + sred[1][k] + sred[2][k] + sred[3][k]);
    }
}

// ---------------------------------------------------------------------------
// K2: sparse corrections at the <=1600 target cells per scale.
// box_t: last write wins (numpy scatter semantics) -> only the last box
//        mapping to a cell contributes. obj_t: union of cells (value 1).
// cls_t: union of (cell,label) elements.
// Correction terms: box: (pb-v)^2 - pb^2 ; obj/cls BCE: -x per target elem.
// One block per (scale, image).
// ---------------------------------------------------------------------------
__global__ __launch_bounds__(64) void corr_kernel(
    const float* __restrict__ p0, const float* __restrict__ p1,
    const float* __restrict__ p2,
    const float* __restrict__ boxes, const int* __restrict__ labels,
    double* __restrict__ acc)
{
    const int s = blockIdx.x / BB;
    const int b = blockIdx.x % BB;
    const float* ps[3] = {p0, p1, p2};
    const int Ws[3] = {64, 32, 16};
    const int W = Ws[s], H = W, hw = W * W;
    const float* pred = ps[s];

    __shared__ int   s_cell[NBOX];
    __shared__ int   s_lab[NBOX];
    __shared__ float s_vx[NBOX], s_vy[NBOX], s_vw[NBOX], s_vh[NBOX];

    const int n = threadIdx.x;
    if (n < NBOX) {
        const float* bp = boxes + ((size_t)b * NBOX + n) * 4;
        float gx = bp[0] * (float)W;
        float gy = bp[1] * (float)H;
        int gi = min((int)gx, W - 1);   // gx > 0 always
        int gj = min((int)gy, H - 1);
        s_cell[n] = gj * W + gi;
        s_lab[n]  = labels[b * NBOX + n];
        s_vx[n] = gx - (float)gi;
        s_vy[n] = gy - (float)gj;
        s_vw[n] = bp[2];
        s_vh[n] = bp[3];
    }
    __syncthreads();

    float cbx = 0.f, cob = 0.f, ccl = 0.f;
    if (n < NBOX) {
        const int cell = s_cell[n], lab = s_lab[n];
        bool lastCell = true, lastCls = true;
        for (int m = n + 1; m < NBOX; ++m) {
            if (s_cell[m] == cell) {
                lastCell = false;
                if (s_lab[m] == lab) lastCls = false;
            }
        }
        const float* pb_base = pred + (size_t)(b * CC) * hw + cell;
        if (lastCell) {
            float vals[4] = {s_vx[n], s_vy[n], s_vw[n], s_vh[n]};
            #pragma unroll
            for (int c = 0; c < 4; ++c) {
                float pb = clip10(pb_base[c * hw]);
                float d  = pb - vals[c];
                cbx += d * d - pb * pb;
            }
            float po = clip10(pb_base[4 * hw]);
            cob -= po;                       // BCE(x,1) - BCE(x,0) = -x
        }
        if (lastCls) {
            float pc = clip10(pb_base[(5 + lab) * hw]);
            ccl -= pc;
        }
    }
    #pragma unroll
    for (int off = 32; off > 0; off >>= 1) {
        cbx += __shfl_down(cbx, off);
        cob += __shfl_down(cob, off);
        ccl += __shfl_down(ccl, off);
    }
    if (threadIdx.x == 0) {
        atomicAdd(&acc[3*s+0], (double)cbx);
        atomicAdd(&acc[3*s+1], (double)cob);
        atomicAdd(&acc[3*s+2], (double)ccl);
    }
}

// ---------------------------------------------------------------------------
// K3: reduce per-block partials (fp64), add corrections, finalize scalar.
// ---------------------------------------------------------------------------
__global__ __launch_bounds__(256) void final_kernel(
    const double* __restrict__ partial, const double* __restrict__ acc,
    float* __restrict__ out, int nb)
{
    double loc[9];
    #pragma unroll
    for (int k = 0; k < 9; ++k) loc[k] = 0.0;
    for (int i = threadIdx.x; i < nb; i += 256) {
        const double* row = partial + (size_t)i * 9;
        #pragma unroll
        for (int k = 0; k < 9; ++k) loc[k] += row[k];
    }
    __shared__ double sd[256];
    __shared__ double tot[9];
    for (int k = 0; k < 9; ++k) {
        sd[threadIdx.x] = loc[k];
        __syncthreads();
        for (int off = 128; off > 0; off >>= 1) {
            if (threadIdx.x < off) sd[threadIdx.x] += sd[threadIdx.x + off];
            __syncthreads();
        }
        if (threadIdx.x == 0) tot[k] = sd[0] + acc[k];
        __syncthreads();
    }
    if (threadIdx.x == 0) {
        const double hws[3] = {4096.0, 1024.0, 256.0};
        double total = 0.0;
        for (int s = 0; s < 3; ++s) {
            double hw  = hws[s];
            double box = tot[3*s+0] / (32.0 * 4.0 * hw);
            double ob  = tot[3*s+1] / (32.0 * hw);
            double cl  = tot[3*s+2] / (32.0 * 80.0 * hw);
            total += 5.0 * box + ob + cl;   // all finite by construction (clip)
        }
        total /= 3.0;
        total = fmin(fmax(total, 0.0), 1000000.0);
        out[0] = (float)total;
    }
}

extern "C" void kernel_launch(void* const* d_in, const int* in_sizes, int n_in,
                              void* d_out, int out_size, void* d_ws, size_t ws_size,
                              hipStream_t stream)
{
    const float* p0     = (const float*)d_in[0];
    const float* p1     = (const float*)d_in[1];
    const float* p2     = (const float*)d_in[2];
    const float* boxes  = (const float*)d_in[3];
    const int*   labels = (const int*)d_in[4];
    float* out = (float*)d_out;

    double* acc     = (double*)d_ws;        // 9 doubles (corrections)
    double* partial = (double*)d_ws + 16;   // GRID1 * 9 doubles

    hipMemsetAsync(acc, 0, 9 * sizeof(double), stream);
    base_kernel<<<GRID1, BLK1, 0, stream>>>(p0, p1, p2, partial);
    corr_kernel<<<3 * BB, 64, 0, stream>>>(p0, p1, p2, boxes, labels, acc);
    final_kernel<<<1, 256, 0, stream>>>(partial, acc, out, GRID1);
}

// Round 2
// 102.459 us; speedup vs baseline: 1.1700x; 1.1700x over previous
//
#include <hip/hip_runtime.h>
#include <math.h>

#define NCLS 80
#define BB   32
#define NBOX 50
#define CC   85   // 5 + NUM_CLASSES

#define GRID1 2048
#define BLK1  256

__device__ __forceinline__ float clip10(float x) {
    return fminf(fmaxf(x, -10.f), 10.f);
}

// BCE with target 0: max(x,0) + log1p(exp(-|x|))
__device__ __forceinline__ float bce0(float x) {
    return fmaxf(x, 0.f) + __logf(1.f + __expf(-fabsf(x)));
}

// ---------------------------------------------------------------------------
// K1 (fused): dense base sums + sparse target corrections.
// Per scale s, per block partials (written fp64, no atomics):
//   part[3s+0] = sum ch 0..3  clip(x)^2   (+ box corrections)
//   part[3s+1] = sum ch 4     BCE(clip,0) (+ obj corrections)
//   part[3s+2] = sum ch 5..84 BCE(clip,0) (+ cls corrections)
// Corrections (blocks 0..95, wave 0): at each target cell, numpy scatter
// semantics = last-write-wins for box_t, set-union for obj_t/cls_t:
//   box: (pb-v)^2 - pb^2 ; obj/cls: BCE(x,1)-BCE(x,0) = -x.
// ---------------------------------------------------------------------------
__global__ __launch_bounds__(BLK1) void base_kernel(
    const float* __restrict__ p0, const float* __restrict__ p1,
    const float* __restrict__ p2,
    const float* __restrict__ boxes, const int* __restrict__ labels,
    double* __restrict__ partial)
{
    const int tid = blockIdx.x * BLK1 + threadIdx.x;
    const int nth = GRID1 * BLK1;
    const float* ps[3] = {p0, p1, p2};
    const int hw4s[3]  = {64*64/4, 32*32/4, 16*16/4};

    float part[9];
    #pragma unroll
    for (int s = 0; s < 3; ++s) {
        const float4* p = (const float4*)ps[s];
        const int hw4 = hw4s[s];                 // 1024/256/64: pow2, div = shift
        const int n4  = BB * CC * hw4;
        float bx = 0.f, ob = 0.f, cl = 0.f;
        for (int i = tid; i < n4; i += nth) {
            float4 v = p[i];
            int c = (i / hw4) % CC;              // channel (uniform within float4)
            float a0 = clip10(v.x), a1 = clip10(v.y);
            float a2 = clip10(v.z), a3 = clip10(v.w);
            if (c < 4) {
                bx += a0*a0 + a1*a1 + a2*a2 + a3*a3;
            } else if (c == 4) {
                ob += bce0(a0) + bce0(a1) + bce0(a2) + bce0(a3);
            } else {
                cl += bce0(a0) + bce0(a1) + bce0(a2) + bce0(a3);
            }
        }
        part[3*s+0] = bx; part[3*s+1] = ob; part[3*s+2] = cl;
    }

    // ---- sparse corrections, folded into this block's partials ----
    __shared__ int   s_cell[NBOX];
    __shared__ int   s_lab[NBOX];
    __shared__ float s_vx[NBOX], s_vy[NBOX], s_vw[NBOX], s_vh[NBOX];

    const bool doCorr = (blockIdx.x < 3 * BB);       // 96 corr blocks
    const int  cs = blockIdx.x / BB;                 // scale
    const int  cb = blockIdx.x % BB;                 // image
    const int  Ws[3] = {64, 32, 16};

    if (doCorr && threadIdx.x < 64) {
        const int n = threadIdx.x;
        const int W = Ws[cs];
        if (n < NBOX) {
            const float* bp = boxes + ((size_t)cb * NBOX + n) * 4;
            float gx = bp[0] * (float)W;
            float gy = bp[1] * (float)W;
            int gi = min((int)gx, W - 1);   // gx > 0 always
            int gj = min((int)gy, W - 1);
            s_cell[n] = gj * W + gi;
            s_lab[n]  = labels[cb * NBOX + n];
            s_vx[n] = gx - (float)gi;
            s_vy[n] = gy - (float)gj;
            s_vw[n] = bp[2];
            s_vh[n] = bp[3];
        }
    }
    __syncthreads();
    if (doCorr && threadIdx.x < 64) {
        const int n = threadIdx.x;
        const int W = Ws[cs], hw = W * W;
        const float* pred = ps[cs];
        float cbx = 0.f, cob = 0.f, ccl = 0.f;
        if (n < NBOX) {
            const int cell = s_cell[n], lab = s_lab[n];
            bool lastCell = true, lastCls = true;
            for (int m = n + 1; m < NBOX; ++m) {
                if (s_cell[m] == cell) {
                    lastCell = false;
                    if (s_lab[m] == lab) lastCls = false;
                }
            }
            const float* pb_base = pred + (size_t)(cb * CC) * hw + cell;
            if (lastCell) {
                float vals[4] = {s_vx[n], s_vy[n], s_vw[n], s_vh[n]};
                #pragma unroll
                for (int c = 0; c < 4; ++c) {
                    float pb = clip10(pb_base[c * hw]);
                    float d  = pb - vals[c];
                    cbx += d * d - pb * pb;
                }
                float po = clip10(pb_base[4 * hw]);
                cob -= po;                       // BCE(x,1) - BCE(x,0) = -x
            }
            if (lastCls) {
                float pc = clip10(pb_base[(5 + lab) * hw]);
                ccl -= pc;
            }
        }
        #pragma unroll
        for (int off = 32; off > 0; off >>= 1) {
            cbx += __shfl_down(cbx, off);
            cob += __shfl_down(cob, off);
            ccl += __shfl_down(ccl, off);
        }
        if (n == 0) {
            part[3*cs+0] += cbx;
            part[3*cs+1] += cob;
            part[3*cs+2] += ccl;
        }
    }

    // ---- wave64 shuffle reduce each of the 9 sums ----
    #pragma unroll
    for (int k = 0; k < 9; ++k) {
        float v = part[k];
        #pragma unroll
        for (int off = 32; off > 0; off >>= 1) v += __shfl_down(v, off);
        part[k] = v;
    }
    __shared__ float sred[BLK1/64][9];
    const int wave = threadIdx.x >> 6;
    const int lane = threadIdx.x & 63;
    if (lane == 0) {
        #pragma unroll
        for (int k = 0; k < 9; ++k) sred[wave][k] = part[k];
    }
    __syncthreads();
    if (threadIdx.x == 0) {
        double* o = partial + (size_t)blockIdx.x * 9;
        #pragma unroll
        for (int k = 0; k < 9; ++k)
            o[k] = (double)(sred[0][k] + sred[1][k] + sred[2][k] + sred[3][k]);
    }
}

// ---------------------------------------------------------------------------
// K2: reduce per-block fp64 partials via wave shuffles, finalize scalar.
// ---------------------------------------------------------------------------
__global__ __launch_bounds__(256) void final_kernel(
    const double* __restrict__ partial, float* __restrict__ out, int nb)
{
    double loc[9];
    #pragma unroll
    for (int k = 0; k < 9; ++k) loc[k] = 0.0;
    for (int i = threadIdx.x; i < nb; i += 256) {
        const double* row = partial + (size_t)i * 9;
        #pragma unroll
        for (int k = 0; k < 9; ++k) loc[k] += row[k];
    }
    // wave64 shuffle reduce (double shuffles = 2x b32)
    #pragma unroll
    for (int k = 0; k < 9; ++k) {
        double v = loc[k];
        #pragma unroll
        for (int off = 32; off > 0; off >>= 1) v += __shfl_down(v, off);
        loc[k] = v;
    }
    __shared__ double sred[4][9];
    const int wave = threadIdx.x >> 6;
    const int lane = threadIdx.x & 63;
    if (lane == 0) {
        #pragma unroll
        for (int k = 0; k < 9; ++k) sred[wave][k] = loc[k];
    }
    __syncthreads();
    if (threadIdx.x == 0) {
        const double hws[3] = {4096.0, 1024.0, 256.0};
        double total = 0.0;
        #pragma unroll
        for (int s = 0; s < 3; ++s) {
            double hw  = hws[s];
            double tb = sred[0][3*s+0] + sred[1][3*s+0] + sred[2][3*s+0] + sred[3][3*s+0];
            double to = sred[0][3*s+1] + sred[1][3*s+1] + sred[2][3*s+1] + sred[3][3*s+1];
            double tc = sred[0][3*s+2] + sred[1][3*s+2] + sred[2][3*s+2] + sred[3][3*s+2];
            double box = tb / (32.0 * 4.0 * hw);
            double ob  = to / (32.0 * hw);
            double cl  = tc / (32.0 * 80.0 * hw);
            total += 5.0 * box + ob + cl;   // all finite by construction (clip)
        }
        total /= 3.0;
        total = fmin(fmax(total, 0.0), 1000000.0);
        out[0] = (float)total;
    }
}

extern "C" void kernel_launch(void* const* d_in, const int* in_sizes, int n_in,
                              void* d_out, int out_size, void* d_ws, size_t ws_size,
                              hipStream_t stream)
{
    const float* p0     = (const float*)d_in[0];
    const float* p1     = (const float*)d_in[1];
    const float* p2     = (const float*)d_in[2];
    const float* boxes  = (const float*)d_in[3];
    const int*   labels = (const int*)d_in[4];
    float* out = (float*)d_out;

    double* partial = (double*)d_ws;   // GRID1 * 9 doubles

    base_kernel<<<GRID1, BLK1, 0, stream>>>(p0, p1, p2, boxes, labels, partial);
    final_kernel<<<1, 256, 0, stream>>>(partial, out, GRID1);
}